// Round 14
// baseline (332.890 us; speedup 1.0000x reference)
//
#include <hip/hip_runtime.h>

typedef __bf16 bf16x8 __attribute__((ext_vector_type(8)));
typedef __bf16 bf16x4 __attribute__((ext_vector_type(4)));
typedef float  f32x4  __attribute__((ext_vector_type(4)));

#define MFMA16(a,b,c) __builtin_amdgcn_mfma_f32_16x16x32_bf16((a),(b),(c),0,0,0)

constexpr int B_ = 256, T_ = 200, DM = 2048, DK = 128;
constexpr int VT_STRIDE = 208;      // Vt[b][v][t], t padded 200->208

// ws layout (bytes)
constexpr size_t OFF_W = 0;                       // Wcat bf16 [384][2048] = 1,572,864
constexpr size_t OFF_Q = 1572864;                 // Q bf16 [51200][128] = 13,107,200
constexpr size_t OFF_K = OFF_Q + 13107200;        // K bf16 [51200][128]
constexpr size_t OFF_V = OFF_K + 13107200;        // Vt bf16 [256][128][208] = 13,631,488

// ---------------- weight conversion: Wq|Wk|Wv fp32 -> Wcat bf16 [384][2048] ----------------
__global__ __launch_bounds__(256) void wconv_kernel(const float* __restrict__ Wq,
                                                    const float* __restrict__ Wk,
                                                    const float* __restrict__ Wv,
                                                    __bf16* __restrict__ Wcat) {
  int idx = (blockIdx.x * 256 + threadIdx.x) * 4;   // < 384*2048 = 786432
  int sel = idx >> 18;                              // /262144 -> 0,1,2
  const float* base = (sel == 0) ? Wq : (sel == 1) ? Wk : Wv;
  float4 f = *(const float4*)(base + (idx - (sel << 18)));
  bf16x4 o;
  o[0] = (__bf16)f.x; o[1] = (__bf16)f.y; o[2] = (__bf16)f.z; o[3] = (__bf16)f.w;
  *(bf16x4*)(Wcat + idx) = o;
}

// ---------------- projection GEMM: C[51200][384] = q(fp32->bf16) @ Wcat^T ----------------
// R14: B NEVER touches LDS (Wcat is L2/L1-resident; per-wave B fragments loaded straight
// to regs, double-set cur/nxt -> compiler's automatic COUNTED vmcnt gives a full step of
// lead). A is the only barrier-coupled object: reg-staged fp32 -> cvt -> bf16 ds_write
// into a 2 x 8 KB double buffer. Per wave-step LDS = 4 reads + 2 writes (R13 had 20+).
// One barrier per step. 128x128 tile, BK=32, 4 waves 2m x 2n (wave tile 64x64, acc=64
// AGPR), __launch_bounds__(256,3) -> 3 blocks/CU = 12 waves/CU (m97 occupancy).
// A-swizzle: phys_chunk = c ^ (row&3) ^ ((row>>2)&3) -> frag reads exactly 2-way (free).
// XCD-triplet job map keeps the 3 N-blocks (Q/K/Vt) of an M-panel on one XCD (A from L2).
__global__ __launch_bounds__(256, 3) void proj_kernel(const float* __restrict__ q,
                                                      const __bf16* __restrict__ Wcat,
                                                      __bf16* __restrict__ Qo,
                                                      __bf16* __restrict__ Ko,
                                                      __bf16* __restrict__ Vt) {
  __shared__ alignas(16) char smem[16384];   // A bf16 [128][32] x2 bufs (8 KB each)

  const int tid  = threadIdx.x;
  const int lane = tid & 63;
  const int w    = tid >> 6;
  const int wm   = w >> 1, wn = w & 1;
  const int lhi  = lane >> 4, llo = lane & 15;

  // XCD-grouped job mapping (1200 = 8 XCDs x 150 jobs; 150 % 3 == 0 -> triplets never straddle)
  const int d  = blockIdx.x;
  const int jj = (d & 7) * 150 + (d >> 3);
  const int mp = jj / 3, nb = jj - mp * 3;
  const int m0 = mp * 128;
  const int col0 = nb * 128;

  f32x4 acc[4][4];
#pragma unroll
  for (int i = 0; i < 4; ++i)
#pragma unroll
    for (int j = 0; j < 4; ++j) acc[i][j] = {0.f, 0.f, 0.f, 0.f};

  // ---- A reg-stage: thread -> row = tid>>1, half = tid&1 (16 fp32 = 64 B, coalesced) ----
  const int arow = tid >> 1, ahalf = tid & 1;
  const float* aptr = q + (size_t)(m0 + arow) * DM + ahalf * 16;
  // A LDS write: row stride 64 B = 4 chunks of 16 B; phys = c ^ (row&3) ^ ((row>>2)&3)
  const int aswz = (arow & 3) ^ ((arow >> 2) & 3);
  const int aw0 = arow * 64 + (((ahalf * 2)     ^ aswz) << 4);
  const int aw1 = arow * 64 + (((ahalf * 2 + 1) ^ aswz) << 4);
  // A frag read: row = wm*64 + i*16 + llo -> swz = (llo&3)^((llo>>2)&3), chunk = lhi
  const int fswz = (llo & 3) ^ ((llo >> 2) & 3);
  const int aro  = (wm * 64 + llo) * 64 + ((lhi ^ fswz) << 4);   // + i*1024

  // ---- B direct-global fragment pointer: lane (llo,lhi) -> row col0+wn*64+j*16+llo ----
  const __bf16* bptr = Wcat + (size_t)(col0 + wn * 64 + llo) * DM + lhi * 8;

  f32x4 sA0a, sA0b, sA0c, sA0d, sA1a, sA1b, sA1c, sA1d;   // two A sets (static names)
  bf16x8 b0f0, b0f1, b0f2, b0f3, b1f0, b1f1, b1f2, b1f3;  // two B sets

#define A_ISSUE(RA, RB, RC, RD, T)                                            \
  { const float* p_ = aptr + (T) * 32;                                        \
    RA = *(const f32x4*)(p_);      RB = *(const f32x4*)(p_ + 4);              \
    RC = *(const f32x4*)(p_ + 8);  RD = *(const f32x4*)(p_ + 12); }

#define B_LOAD(F0, F1, F2, F3, T)                                             \
  { const __bf16* p_ = bptr + (size_t)(T) * 32;                               \
    F0 = *(const bf16x8*)(p_);                                                \
    F1 = *(const bf16x8*)(p_ + (size_t)16 * DM);                              \
    F2 = *(const bf16x8*)(p_ + (size_t)32 * DM);                              \
    F3 = *(const bf16x8*)(p_ + (size_t)48 * DM); }

#define A_PUB(RA, RB, RC, RD, BUF)                                            \
  { char* la_ = smem + (BUF) * 8192;                                          \
    bf16x8 p0, p1;                                                            \
    p0[0]=(__bf16)RA[0]; p0[1]=(__bf16)RA[1]; p0[2]=(__bf16)RA[2]; p0[3]=(__bf16)RA[3]; \
    p0[4]=(__bf16)RB[0]; p0[5]=(__bf16)RB[1]; p0[6]=(__bf16)RB[2]; p0[7]=(__bf16)RB[3]; \
    p1[0]=(__bf16)RC[0]; p1[1]=(__bf16)RC[1]; p1[2]=(__bf16)RC[2]; p1[3]=(__bf16)RC[3]; \
    p1[4]=(__bf16)RD[0]; p1[5]=(__bf16)RD[1]; p1[6]=(__bf16)RD[2]; p1[7]=(__bf16)RD[3]; \
    *(bf16x8*)(la_ + aw0) = p0;                                               \
    *(bf16x8*)(la_ + aw1) = p1; }

#define COMPUTE(BUF, F0, F1, F2, F3)                                          \
  { const char* la_ = smem + (BUF) * 8192;                                    \
    bf16x8 af[4];                                                             \
    _Pragma("unroll")                                                         \
    for (int i = 0; i < 4; ++i) af[i] = *(const bf16x8*)(la_ + aro + i * 1024); \
    _Pragma("unroll")                                                         \
    for (int i = 0; i < 4; ++i) {                                             \
      acc[i][0] = MFMA16(af[i], F0, acc[i][0]);                               \
      acc[i][1] = MFMA16(af[i], F1, acc[i][1]);                               \
      acc[i][2] = MFMA16(af[i], F2, acc[i][2]);                               \
      acc[i][3] = MFMA16(af[i], F3, acc[i][3]);                               \
    } }

#define LGKM0() asm volatile("s_waitcnt lgkmcnt(0)" ::: "memory")
#define BAR()   { __builtin_amdgcn_s_barrier(); asm volatile("" ::: "memory"); }

  // ---- prologue: A(0)->s0->buf0; A(1)->s1 in flight; B(0)->b0 ----
  A_ISSUE(sA0a, sA0b, sA0c, sA0d, 0);
  B_LOAD(b0f0, b0f1, b0f2, b0f3, 0);
  A_ISSUE(sA1a, sA1b, sA1c, sA1d, 1);
  A_PUB(sA0a, sA0b, sA0c, sA0d, 0);   // compiler counted-waits A(0) only
  LGKM0();
  BAR();

  // ---- steady: u = 0..59 as 30 pairs ----
  for (int tp = 0; tp < 30; ++tp) {
    const int u = tp * 2;
    { // even u: compute buf0 with B(u)=b0; publish A(u+1)->buf1; issue A(u+2), B(u+1)
      B_LOAD(b1f0, b1f1, b1f2, b1f3, u + 1);
      A_ISSUE(sA0a, sA0b, sA0c, sA0d, u + 2);
      COMPUTE(0, b0f0, b0f1, b0f2, b0f3);
      A_PUB(sA1a, sA1b, sA1c, sA1d, 1);
      LGKM0();
      BAR();
    }
    { // odd u+1: compute buf1 with B(u+1)=b1; publish A(u+2)->buf0; issue A(u+3), B(u+2)
      B_LOAD(b0f0, b0f1, b0f2, b0f3, u + 2);
      A_ISSUE(sA1a, sA1b, sA1c, sA1d, u + 3);
      COMPUTE(1, b1f0, b1f1, b1f2, b1f3);
      A_PUB(sA0a, sA0b, sA0c, sA0d, 0);
      LGKM0();
      BAR();
    }
  }
  { // u = 60 (even, buf0)
    B_LOAD(b1f0, b1f1, b1f2, b1f3, 61);
    A_ISSUE(sA0a, sA0b, sA0c, sA0d, 62);
    COMPUTE(0, b0f0, b0f1, b0f2, b0f3);
    A_PUB(sA1a, sA1b, sA1c, sA1d, 1);
    LGKM0();
    BAR();
  }
  { // u = 61 (odd, buf1)
    B_LOAD(b0f0, b0f1, b0f2, b0f3, 62);
    A_ISSUE(sA1a, sA1b, sA1c, sA1d, 63);
    COMPUTE(1, b1f0, b1f1, b1f2, b1f3);
    A_PUB(sA0a, sA0b, sA0c, sA0d, 0);
    LGKM0();
    BAR();
  }
  { // u = 62 (even, buf0): last A publish (A(63))
    B_LOAD(b1f0, b1f1, b1f2, b1f3, 63);
    COMPUTE(0, b0f0, b0f1, b0f2, b0f3);
    A_PUB(sA1a, sA1b, sA1c, sA1d, 1);
    LGKM0();
    BAR();
  }
  { // u = 63 (odd, buf1): final
    COMPUTE(1, b1f0, b1f1, b1f2, b1f3);
  }
#undef A_ISSUE
#undef B_LOAD
#undef A_PUB
#undef COMPUTE
#undef LGKM0
#undef BAR

  // epilogue: nb selects destination (block-uniform branch)
  if (nb == 0) {
#pragma unroll
    for (int i = 0; i < 4; ++i)
#pragma unroll
      for (int r = 0; r < 4; ++r) {
        int row = m0 + wm * 64 + i * 16 + lhi * 4 + r;
#pragma unroll
        for (int j = 0; j < 4; ++j)
          Qo[(size_t)row * DK + wn * 64 + j * 16 + llo] = (__bf16)acc[i][j][r];
      }
  } else if (nb == 1) {
#pragma unroll
    for (int i = 0; i < 4; ++i)
#pragma unroll
      for (int r = 0; r < 4; ++r) {
        int row = m0 + wm * 64 + i * 16 + lhi * 4 + r;
#pragma unroll
        for (int j = 0; j < 4; ++j)
          Ko[(size_t)row * DK + wn * 64 + j * 16 + llo] = (__bf16)acc[i][j][r];
      }
  } else {
#pragma unroll
    for (int i = 0; i < 4; ++i)
#pragma unroll
      for (int r = 0; r < 4; ++r) {
        int row = m0 + wm * 64 + i * 16 + lhi * 4 + r;
        int b = row / 200;
        int t = row - b * 200;
#pragma unroll
        for (int j = 0; j < 4; ++j) {
          int col = wn * 64 + j * 16 + llo;
          Vt[((size_t)b * DK + col) * VT_STRIDE + t] = (__bf16)acc[i][j][r];
        }
      }
  }
}

// ---------------- attention: one WG per (batch, 64-query block), templated on block ----------------
template <int QB>
__global__ __launch_bounds__(256, 1) void attn_kernel(const __bf16* __restrict__ Qg,
                                                      const __bf16* __restrict__ Kg,
                                                      const __bf16* __restrict__ Vt,
                                                      const int* __restrict__ padm,
                                                      float* __restrict__ out) {
  constexpr int Q0     = QB * 64;
  constexpr int KMAX   = (Q0 + 64 < T_) ? (Q0 + 64) : T_;   // 64,128,192,200 (causal bound)
  constexpr int KTILES = (KMAX + 15) / 16;                  // 4,8,12,13
  constexpr int KCC    = (KMAX + 31) / 32;                  // 2,4,6,7
  constexpr int KT16   = KTILES * 16;                       // 64,128,192,208
  constexpr int KP     = KCC * 32;                          // 64,128,192,224
  constexpr int VS     = KP + 8;                            // padded stride (bank spread)

  __shared__ __bf16 sK[KT16][136];
  __shared__ __bf16 sV[128][VS];       // V^T: [v][t]
  __shared__ __bf16 sP[4][16][VS];     // per-wave P transpose buffer
  __shared__ float  sMask[KT16];

  const int tid  = threadIdx.x;
  const int lane = tid & 63;
  const int w    = tid >> 6;
  const int b    = blockIdx.x;
  const int lhi  = lane >> 4, llo = lane & 15;

  // additive key mask: 0 valid, -1e30 for pad / t>=KMAX
  for (int t = tid; t < KT16; t += 256) {
    float mv = -1e30f;
    if (t < KMAX && padm[b * T_ + t] == 0) mv = 0.0f;
    sMask[t] = mv;
  }
  // stage K rows [0, KT16) (rows >= T_ clamped; they get masked anyway)
  for (int cid = tid; cid < KT16 * 16; cid += 256) {
    int t = cid >> 4, c = (cid & 15) * 8;
    int tg = (t < T_) ? t : (T_ - 1);
    *(bf16x8*)&sK[t][c] = *(const bf16x8*)(Kg + ((size_t)b * T_ + tg) * DK + c);
  }
  // stage V^T: [128][KP), zeros beyond Vt's 208 columns
  {
    constexpr int NCH = KP / 8;
    for (int cid = tid; cid < 128 * NCH; cid += 256) {
      int v = cid / NCH, t0 = (cid % NCH) * 8;
      bf16x8 val;
      if (t0 < VT_STRIDE) {
        val = *(const bf16x8*)(Vt + ((size_t)b * DK + v) * VT_STRIDE + t0);
      } else {
#pragma unroll
        for (int jz = 0; jz < 8; ++jz) val[jz] = (__bf16)0.0f;
      }
      *(bf16x8*)&sV[v][t0] = val;
    }
  }
  // zero P pad columns [KT16, KP) (only QB==3: 208..224)
  if constexpr (KT16 < KP) {
    constexpr int NC = (KP - KT16) / 8;
    for (int idx = tid; idx < 4 * 16 * NC; idx += 256) {
      int ww = idx / (16 * NC);
      int rem = idx % (16 * NC);
      int row = rem / NC, cc = (rem % NC) * 8;
      bf16x8 z;
#pragma unroll
      for (int jz = 0; jz < 8; ++jz) z[jz] = (__bf16)0.0f;
      *(bf16x8*)&sP[ww][row][KT16 + cc] = z;
    }
  }
  __syncthreads();

  // Q fragments in registers (A-frag: row = llo, k-chunk = lhi)
  const int q0w = Q0 + w * 16;
  bf16x8 qf[4];
  {
    int qrow = q0w + llo;
    if (qrow > T_ - 1) qrow = T_ - 1;
    const __bf16* qp = Qg + ((size_t)b * T_ + qrow) * DK + lhi * 8;
#pragma unroll
    for (int kk = 0; kk < 4; ++kk) qf[kk] = *(const bf16x8*)(qp + kk * 32);
  }

  // scores: S[16q x KT16] per wave, kept in registers
  float sc[KTILES][4];
  const float scale = 0.022097086912079608f;   // 1/sqrt(2048)
#pragma unroll
  for (int tt = 0; tt < KTILES; ++tt) {
    f32x4 s = {0.f, 0.f, 0.f, 0.f};
    const __bf16* kp = &sK[tt * 16 + llo][lhi * 8];
#pragma unroll
    for (int kk = 0; kk < 4; ++kk) {
      bf16x8 kf = *(const bf16x8*)(kp + kk * 32);
      s = MFMA16(qf[kk], kf, s);
    }
    const int t = tt * 16 + llo;
    const float madd = sMask[t];
#pragma unroll
    for (int r = 0; r < 4; ++r) {
      int qq = q0w + lhi * 4 + r;               // C layout: row = lhi*4+r, col = llo
      float v = fmaf(s[r], scale, madd);
      sc[tt][r] = (t > qq) ? -1e30f : v;        // overwrite-style causal mask (NaN-safe)
    }
  }

  // row softmax: reduce across the 16-lane col group per accumulator row
#pragma unroll
  for (int r = 0; r < 4; ++r) {
    float mm = -3e38f;
#pragma unroll
    for (int tt = 0; tt < KTILES; ++tt) mm = fmaxf(mm, sc[tt][r]);
#pragma unroll
    for (int off = 1; off < 16; off <<= 1) mm = fmaxf(mm, __shfl_xor(mm, off));
    float ss = 0.f;
#pragma unroll
    for (int tt = 0; tt < KTILES; ++tt) { float e = __expf(sc[tt][r] - mm); sc[tt][r] = e; ss += e; }
#pragma unroll
    for (int off = 1; off < 16; off <<= 1) ss += __shfl_xor(ss, off);
    float inv = 1.0f / ss;
#pragma unroll
    for (int tt = 0; tt < KTILES; ++tt) sc[tt][r] *= inv;
  }

  // P -> LDS (transpose through memory for the PV A-fragment)
#pragma unroll
  for (int tt = 0; tt < KTILES; ++tt) {
    int t = tt * 16 + llo;
#pragma unroll
    for (int r = 0; r < 4; ++r) sP[w][lhi * 4 + r][t] = (__bf16)sc[tt][r];
  }
  __syncthreads();

  // PV: out[16q x 128v] = P[16 x KP] @ V[KP x 128]
  f32x4 oacc[8];
#pragma unroll
  for (int vt = 0; vt < 8; ++vt) oacc[vt] = {0.f, 0.f, 0.f, 0.f};
#pragma unroll
  for (int kc = 0; kc < KCC; ++kc) {
    bf16x8 pa = *(const bf16x8*)&sP[w][llo][kc * 32 + lhi * 8];
#pragma unroll
    for (int vt = 0; vt < 8; ++vt) {
      bf16x8 vb = *(const bf16x8*)&sV[vt * 16 + llo][kc * 32 + lhi * 8];
      oacc[vt] = MFMA16(pa, vb, oacc[vt]);
    }
  }

  // write fp32 output
#pragma unroll
  for (int vt = 0; vt < 8; ++vt) {
#pragma unroll
    for (int r = 0; r < 4; ++r) {
      int qq = q0w + lhi * 4 + r;
      if (qq < T_) out[((size_t)b * T_ + qq) * DK + vt * 16 + llo] = oacc[vt][r];
    }
  }
}

extern "C" void kernel_launch(void* const* d_in, const int* in_sizes, int n_in,
                              void* d_out, int out_size, void* d_ws, size_t ws_size,
                              hipStream_t stream) {
  const float* q    = (const float*)d_in[0];
  const int*   padm = (const int*)d_in[1];
  const float* Wq   = (const float*)d_in[2];
  const float* Wk   = (const float*)d_in[3];
  const float* Wv   = (const float*)d_in[4];
  float* out        = (float*)d_out;

  char* ws = (char*)d_ws;
  __bf16* Wcat = (__bf16*)(ws + OFF_W);
  __bf16* Qb   = (__bf16*)(ws + OFF_Q);
  __bf16* Kb   = (__bf16*)(ws + OFF_K);
  __bf16* Vtb  = (__bf16*)(ws + OFF_V);

  wconv_kernel<<<768, 256, 0, stream>>>(Wq, Wk, Wv, Wcat);
  proj_kernel<<<1200, 256, 0, stream>>>(q, Wcat, Qb, Kb, Vtb);
  attn_kernel<0><<<256, 256, 0, stream>>>(Qb, Kb, Vtb, padm, out);
  attn_kernel<1><<<256, 256, 0, stream>>>(Qb, Kb, Vtb, padm, out);
  attn_kernel<2><<<256, 256, 0, stream>>>(Qb, Kb, Vtb, padm, out);
  attn_kernel<3><<<256, 256, 0, stream>>>(Qb, Kb, Vtb, padm, out);
}